// Round 1
// baseline (6468.369 us; speedup 1.0000x reference)
//
#include <hip/hip_runtime.h>
#include <math.h>

#define D_MODEL 512
#define NHEAD   8
#define DKH     64
#define NLAYER  6
#define FFDIM   2048
#define VOCAB   512
#define BB      4
#define SS      1024
#define NROWS   (BB*SS)   // 4096

__device__ __forceinline__ float wave_sum(float v) {
#pragma unroll
    for (int o = 32; o > 0; o >>= 1) v += __shfl_xor(v, o);
    return v;
}
__device__ __forceinline__ float wave_max(float v) {
#pragma unroll
    for (int o = 32; o > 0; o >>= 1) v = fmaxf(v, __shfl_xor(v, o));
    return v;
}

// ---------------------------------------------------------------- embedding
// x[row, d] = emb[ids[row], d] * sqrt(512) + pe[s, d]
__global__ __launch_bounds__(512) void embed_kernel(
    const int* __restrict__ ids, const float* __restrict__ emb,
    float* __restrict__ x)
{
    int row = blockIdx.x;          // 0..4095  (b*SS + s)
    int d   = threadIdx.x;         // 0..511
    int s   = row & (SS - 1);
    int tok = ids[row];
    // div = exp(-(2*(d/2)) * ln(10000)/512), even d -> sin, odd -> cos
    float div = expf(-(float)(d & ~1) * 0.0179889460390586f);
    float arg = (float)s * div;
    float pe  = (d & 1) ? cosf(arg) : sinf(arg);
    x[(size_t)row * D_MODEL + d] = emb[(size_t)tok * D_MODEL + d] * 22.62741699796952f + pe;
}

// ---------------------------------------------------------------- layernorm
// out[row,:] = (x - mean) * rsqrt(var + eps) * g + b   (block per row, 512 thr)
__global__ __launch_bounds__(512) void ln_kernel(
    const float* __restrict__ x, const float* __restrict__ g,
    const float* __restrict__ b, float* __restrict__ out)
{
    int row = blockIdx.x;
    int d   = threadIdx.x;
    int wave = d >> 6, lane = d & 63;
    __shared__ float red[8];

    float v = x[(size_t)row * D_MODEL + d];
    float s = wave_sum(v);
    if (lane == 0) red[wave] = s;
    __syncthreads();
    float tot = 0.f;
#pragma unroll
    for (int i = 0; i < 8; ++i) tot += red[i];
    float mu = tot * (1.0f / D_MODEL);
    float c  = v - mu;
    __syncthreads();
    float s2 = wave_sum(c * c);
    if (lane == 0) red[wave] = s2;
    __syncthreads();
    float tot2 = 0.f;
#pragma unroll
    for (int i = 0; i < 8; ++i) tot2 += red[i];
    float var = tot2 * (1.0f / D_MODEL);
    out[(size_t)row * D_MODEL + d] = c * (1.0f / sqrtf(var + 1e-5f)) * g[d] + b[d];
}

// ---------------------------------------------------------------- GEMM
// C[m,n] = sum_k A[m,k] * W[n,k] (+ bias[n]) (+ res[m,n]) (+ relu)
// BM=64 BN=64 BK=16, 128 threads, 8x4 per-thread tile.
template<bool RELU, bool RES>
__global__ __launch_bounds__(128) void gemm_kernel(
    const float* __restrict__ A, const float* __restrict__ W,
    const float* __restrict__ bias, const float* __restrict__ res,
    float* __restrict__ C, int M, int N, int K)
{
    const int BM = 64, BN = 64, BK = 16;
    __shared__ __align__(16) float As[BK][BM + 4];   // [k][m], pad keeps 16B row align
    __shared__ __align__(16) float Ws[BK][BN + 4];   // [k][n]

    int t    = threadIdx.x;
    int col0 = blockIdx.x * BN;
    int row0 = blockIdx.y * BM;
    int tm0  = (t >> 4) << 3;   // 0,8,..,56
    int tn0  = (t & 15) << 2;   // 0,4,..,60

    int ra = t >> 1;            // staging row 0..63
    int ka = (t & 1) * 8;       // staging k-offset 0 or 8

    float acc[8][4];
#pragma unroll
    for (int i = 0; i < 8; ++i)
#pragma unroll
        for (int j = 0; j < 4; ++j) acc[i][j] = 0.f;

    for (int k0 = 0; k0 < K; k0 += BK) {
        __syncthreads();
        {
            const float* ap = A + (size_t)(row0 + ra) * K + k0 + ka;
            float4 a0 = *(const float4*)ap;
            float4 a1 = *(const float4*)(ap + 4);
            As[ka + 0][ra] = a0.x; As[ka + 1][ra] = a0.y;
            As[ka + 2][ra] = a0.z; As[ka + 3][ra] = a0.w;
            As[ka + 4][ra] = a1.x; As[ka + 5][ra] = a1.y;
            As[ka + 6][ra] = a1.z; As[ka + 7][ra] = a1.w;
            const float* wp = W + (size_t)(col0 + ra) * K + k0 + ka;
            float4 b0 = *(const float4*)wp;
            float4 b1 = *(const float4*)(wp + 4);
            Ws[ka + 0][ra] = b0.x; Ws[ka + 1][ra] = b0.y;
            Ws[ka + 2][ra] = b0.z; Ws[ka + 3][ra] = b0.w;
            Ws[ka + 4][ra] = b1.x; Ws[ka + 5][ra] = b1.y;
            Ws[ka + 6][ra] = b1.z; Ws[ka + 7][ra] = b1.w;
        }
        __syncthreads();
#pragma unroll
        for (int k = 0; k < BK; ++k) {
            float a[8], bb[4];
            *(float4*)&a[0] = *(const float4*)&As[k][tm0];
            *(float4*)&a[4] = *(const float4*)&As[k][tm0 + 4];
            *(float4*)&bb[0] = *(const float4*)&Ws[k][tn0];
#pragma unroll
            for (int i = 0; i < 8; ++i)
#pragma unroll
                for (int j = 0; j < 4; ++j) acc[i][j] += a[i] * bb[j];
        }
    }

#pragma unroll
    for (int i = 0; i < 8; ++i) {
        int row = row0 + tm0 + i;
        int n   = col0 + tn0;
        float4 cv;
        cv.x = acc[i][0]; cv.y = acc[i][1]; cv.z = acc[i][2]; cv.w = acc[i][3];
        if (bias) {
            float4 bv = *(const float4*)(bias + n);
            cv.x += bv.x; cv.y += bv.y; cv.z += bv.z; cv.w += bv.w;
        }
        if (RES) {
            float4 rv = *(const float4*)(res + (size_t)row * N + n);
            cv.x += rv.x; cv.y += rv.y; cv.z += rv.z; cv.w += rv.w;
        }
        if (RELU) {
            cv.x = fmaxf(cv.x, 0.f); cv.y = fmaxf(cv.y, 0.f);
            cv.z = fmaxf(cv.z, 0.f); cv.w = fmaxf(cv.w, 0.f);
        }
        *(float4*)(C + (size_t)row * N + n) = cv;
    }
}

// ---------------------------------------------------------------- attention
// One block = 4 consecutive queries of one (b,h); wave w handles query qt*4+w.
// Online softmax over 64-key tiles staged in LDS.
__global__ __launch_bounds__(256) void attn_kernel(
    const float* __restrict__ qb, const float* __restrict__ kb,
    const float* __restrict__ vb, const int* __restrict__ am,
    float* __restrict__ ob)
{
    __shared__ float Ks[64][65];
    __shared__ float Vs[64][65];
    __shared__ float qs[4][64];

    int t    = threadIdx.x;
    int wave = t >> 6, lane = t & 63;
    int grp  = blockIdx.x;             // (b*NHEAD+h)*256 + qt
    int qt   = grp & (SS / 4 - 1);     // 0..255
    int bh   = grp >> 8;               // 0..31
    int b    = bh >> 3, h = bh & 7;
    int qi   = qt * 4 + wave;

    const float* qrow = qb + ((size_t)(b * SS + qi)) * D_MODEL + h * DKH;
    float qreg = qrow[lane];
    qs[wave][lane] = qreg;

    float m_run = -1e30f, l_run = 0.f, acc = 0.f;
    int qmax = qt * 4 + 3;
    int nt   = qmax / 64 + 1;

    const float* Kbase = kb + ((size_t)(b * SS)) * D_MODEL + h * DKH;
    const float* Vbase = vb + ((size_t)(b * SS)) * D_MODEL + h * DKH;

    for (int kt = 0; kt < nt; ++kt) {
        __syncthreads();
        {
            int r  = t >> 2;
            int c0 = (t & 3) * 16;
            const float* kr = Kbase + (size_t)(kt * 64 + r) * D_MODEL;
            const float* vr = Vbase + (size_t)(kt * 64 + r) * D_MODEL;
#pragma unroll
            for (int j = 0; j < 16; j += 4) {
                float4 kv = *(const float4*)(kr + c0 + j);
                float4 vv = *(const float4*)(vr + c0 + j);
                Ks[r][c0 + j] = kv.x; Ks[r][c0 + j + 1] = kv.y;
                Ks[r][c0 + j + 2] = kv.z; Ks[r][c0 + j + 3] = kv.w;
                Vs[r][c0 + j] = vv.x; Vs[r][c0 + j + 1] = vv.y;
                Vs[r][c0 + j + 2] = vv.z; Vs[r][c0 + j + 3] = vv.w;
            }
        }
        __syncthreads();

        int kk = kt * 64 + lane;
        float sc = 0.f;
#pragma unroll
        for (int d = 0; d < 64; ++d) sc += qs[wave][d] * Ks[lane][d];
        bool valid = (kk <= qi) && (am[b * SS + kk] != 0);
        sc = valid ? sc * 0.125f : -1e9f;

        float tmax  = wave_max(sc);
        float m_new = fmaxf(m_run, tmax);
        float p     = __expf(sc - m_new);
        float tsum  = wave_sum(p);
        float scale = __expf(m_run - m_new);
        l_run = l_run * scale + tsum;
        acc  *= scale;
#pragma unroll
        for (int j = 0; j < 64; ++j) {
            float pj = __shfl(p, j);
            acc += pj * Vs[j][lane];
        }
        m_run = m_new;
    }

    ob[((size_t)(b * SS + qi)) * D_MODEL + h * DKH + lane] = acc / l_run;
}

// ---------------------------------------------------------------- launch
extern "C" void kernel_launch(void* const* d_in, const int* in_sizes, int n_in,
                              void* d_out, int out_size, void* d_ws, size_t ws_size,
                              hipStream_t stream)
{
    const int*   ids   = (const int*)d_in[0];
    const int*   am    = (const int*)d_in[1];
    const float* emb   = (const float*)d_in[2];
    const float* wq    = (const float*)d_in[3];
    const float* bq    = (const float*)d_in[4];
    const float* wk    = (const float*)d_in[5];
    const float* bk    = (const float*)d_in[6];
    const float* wv    = (const float*)d_in[7];
    const float* bv    = (const float*)d_in[8];
    const float* wo    = (const float*)d_in[9];
    const float* bo    = (const float*)d_in[10];
    const float* ln1g  = (const float*)d_in[11];
    const float* ln1b  = (const float*)d_in[12];
    const float* w1    = (const float*)d_in[13];
    const float* b1    = (const float*)d_in[14];
    const float* w2    = (const float*)d_in[15];
    const float* b2    = (const float*)d_in[16];
    const float* ln2g  = (const float*)d_in[17];
    const float* ln2b  = (const float*)d_in[18];
    const float* lnfg  = (const float*)d_in[19];
    const float* lnfb  = (const float*)d_in[20];
    const float* lmw   = (const float*)d_in[21];

    const size_t nm = (size_t)NROWS * D_MODEL;   // 2M floats
    float* h  = (float*)d_ws;
    float* h2 = h  + nm;
    float* qv = h2 + nm;
    float* kv = qv + nm;
    float* vv = kv + nm;
    float* ov = vv + nm;
    float* fb = qv;                              // NROWS*FFDIM = 4*nm, reuses q/k/v/o

    const dim3 gs_d (D_MODEL / 64, NROWS / 64);  // (8, 64)
    const dim3 gs_ff(FFDIM  / 64, NROWS / 64);   // (32, 64)

    embed_kernel<<<NROWS, 512, 0, stream>>>(ids, emb, h);

    for (int l = 0; l < NLAYER; ++l) {
        const size_t dd = (size_t)l * D_MODEL * D_MODEL;
        const size_t fd = (size_t)l * FFDIM * D_MODEL;
        gemm_kernel<false, false><<<gs_d, 128, 0, stream>>>(
            h, wq + dd, bq + l * D_MODEL, nullptr, qv, NROWS, D_MODEL, D_MODEL);
        gemm_kernel<false, false><<<gs_d, 128, 0, stream>>>(
            h, wk + dd, bk + l * D_MODEL, nullptr, kv, NROWS, D_MODEL, D_MODEL);
        gemm_kernel<false, false><<<gs_d, 128, 0, stream>>>(
            h, wv + dd, bv + l * D_MODEL, nullptr, vv, NROWS, D_MODEL, D_MODEL);

        attn_kernel<<<BB * NHEAD * (SS / 4), 256, 0, stream>>>(qv, kv, vv, am, ov);

        gemm_kernel<false, true><<<gs_d, 128, 0, stream>>>(
            ov, wo + dd, bo + l * D_MODEL, h, h2, NROWS, D_MODEL, D_MODEL);
        ln_kernel<<<NROWS, 512, 0, stream>>>(h2, ln1g + l * D_MODEL, ln1b + l * D_MODEL, h);

        gemm_kernel<true, false><<<gs_ff, 128, 0, stream>>>(
            h, w1 + fd, b1 + l * FFDIM, nullptr, fb, NROWS, FFDIM, D_MODEL);
        gemm_kernel<false, true><<<gs_d, 128, 0, stream>>>(
            fb, w2 + fd, b2 + l * D_MODEL, h, h2, NROWS, D_MODEL, FFDIM);
        ln_kernel<<<NROWS, 512, 0, stream>>>(h2, ln2g + l * D_MODEL, ln2b + l * D_MODEL, h);
    }

    ln_kernel<<<NROWS, 512, 0, stream>>>(h, lnfg, lnfb, h);
    gemm_kernel<false, false><<<gs_d, 128, 0, stream>>>(
        h, lmw, nullptr, nullptr, (float*)d_out, NROWS, VOCAB, D_MODEL);
}

// Round 2
// 3840.936 us; speedup vs baseline: 1.6841x; 1.6841x over previous
//
#include <hip/hip_runtime.h>
#include <math.h>

#define D_MODEL 512
#define NHEAD   8
#define DKH     64
#define NLAYER  6
#define FFDIM   2048
#define VOCAB   512
#define BB      4
#define SS      1024
#define NROWS   4096

typedef unsigned short ushort_t;
typedef short short8 __attribute__((ext_vector_type(8)));
typedef float f32x4  __attribute__((ext_vector_type(4)));

__device__ __forceinline__ float bf2f(ushort_t u) {
    union { float f; unsigned int i; } x; x.i = ((unsigned int)u) << 16; return x.f;
}
__device__ __forceinline__ ushort_t f2bf(float f) {
    union { float f; unsigned int i; } x; x.f = f;
    unsigned int r = x.i + 0x7FFFu + ((x.i >> 16) & 1u);
    return (ushort_t)(r >> 16);
}
__device__ __forceinline__ void gload_lds16(const void* g, void* l) {
    __builtin_amdgcn_global_load_lds(
        (const __attribute__((address_space(1))) void*)g,
        (__attribute__((address_space(3))) void*)l, 16, 0, 0);
}

// ------------------------------------------------------------- weight convert
// per-layer: wq|wk|wv -> wl[0:786432), wo -> [786432:1048576), w1 -> [1048576:2097152),
// w2 -> [2097152:3145728). Also bq|bk|bv -> bqkv[1536] f32.
__global__ __launch_bounds__(256) void cvt_layer(
    const float* __restrict__ wq, const float* __restrict__ wk, const float* __restrict__ wv,
    const float* __restrict__ wo, const float* __restrict__ w1, const float* __restrict__ w2,
    const float* __restrict__ bq, const float* __restrict__ bk, const float* __restrict__ bv,
    ushort_t* __restrict__ wl, float* __restrict__ bqkv)
{
    int idx = blockIdx.x * 256 + threadIdx.x;   // quad id, 786432 total
    int e = idx * 4;
    float4 v;
    if (e < 786432) {
        if (e < 262144)       v = *(const float4*)(wq + e);
        else if (e < 524288)  v = *(const float4*)(wk + (e - 262144));
        else                  v = *(const float4*)(wv + (e - 524288));
    } else if (e < 1048576)   v = *(const float4*)(wo + (e - 786432));
    else if (e < 2097152)     v = *(const float4*)(w1 + (e - 1048576));
    else                      v = *(const float4*)(w2 + (e - 2097152));
    union { ushort_t u[4]; uint2 q; } pk;
    pk.u[0] = f2bf(v.x); pk.u[1] = f2bf(v.y); pk.u[2] = f2bf(v.z); pk.u[3] = f2bf(v.w);
    *(uint2*)(wl + e) = pk.q;
    if (idx < 384) {
        int b4 = idx * 4;
        float4 bv4;
        if (b4 < 512)       bv4 = *(const float4*)(bq + b4);
        else if (b4 < 1024) bv4 = *(const float4*)(bk + (b4 - 512));
        else                bv4 = *(const float4*)(bv + (b4 - 1024));
        *(float4*)(bqkv + b4) = bv4;
    }
}

__global__ __launch_bounds__(256) void cvt_simple(
    const float* __restrict__ src, ushort_t* __restrict__ dst)
{
    int e = (blockIdx.x * 256 + threadIdx.x) * 4;
    float4 v = *(const float4*)(src + e);
    union { ushort_t u[4]; uint2 q; } pk;
    pk.u[0] = f2bf(v.x); pk.u[1] = f2bf(v.y); pk.u[2] = f2bf(v.z); pk.u[3] = f2bf(v.w);
    *(uint2*)(dst + e) = pk.q;
}

// ---------------------------------------------------------------- embedding
__global__ __launch_bounds__(512) void embed_kernel(
    const int* __restrict__ ids, const float* __restrict__ emb,
    float* __restrict__ xf, ushort_t* __restrict__ xb)
{
    int row = blockIdx.x;
    int d   = threadIdx.x;
    int s   = row & (SS - 1);
    int tok = ids[row];
    float div = expf(-(float)(d & ~1) * 0.0179889460390586f);
    float arg = (float)s * div;
    float pe  = (d & 1) ? cosf(arg) : sinf(arg);
    float v = emb[(size_t)tok * D_MODEL + d] * 22.62741699796952f + pe;
    xf[(size_t)row * D_MODEL + d] = v;
    xb[(size_t)row * D_MODEL + d] = f2bf(v);
}

// ---------------------------------------------------------------- layernorm
__global__ __launch_bounds__(512) void ln_kernel(
    const float* __restrict__ x, const float* __restrict__ g,
    const float* __restrict__ b, float* __restrict__ outf, ushort_t* __restrict__ outb)
{
    int row = blockIdx.x;
    int d   = threadIdx.x;
    int wave = d >> 6, lane = d & 63;
    __shared__ float red[8];

    float v = x[(size_t)row * D_MODEL + d];
    float s = v;
#pragma unroll
    for (int o = 32; o > 0; o >>= 1) s += __shfl_xor(s, o);
    if (lane == 0) red[wave] = s;
    __syncthreads();
    float tot = 0.f;
#pragma unroll
    for (int i = 0; i < 8; ++i) tot += red[i];
    float mu = tot * (1.0f / D_MODEL);
    float c  = v - mu;
    __syncthreads();
    float s2 = c * c;
#pragma unroll
    for (int o = 32; o > 0; o >>= 1) s2 += __shfl_xor(s2, o);
    if (lane == 0) red[wave] = s2;
    __syncthreads();
    float tot2 = 0.f;
#pragma unroll
    for (int i = 0; i < 8; ++i) tot2 += red[i];
    float var = tot2 * (1.0f / D_MODEL);
    float y = c * (1.0f / sqrtf(var + 1e-5f)) * g[d] + b[d];
    outf[(size_t)row * D_MODEL + d] = y;
    outb[(size_t)row * D_MODEL + d] = f2bf(y);
}

// ---------------------------------------------------------------- MFMA GEMM
// C[m,n] = sum_k A[m,k]*W[n,k] (+bias) (+res) (+relu); A,W bf16 K-major; acc f32.
// m97 structure: BMxBN tile, BK=32, 256 thr (4 waves 2x2), global_load_lds staging.
template<int BM, int BN, bool RELU, bool RES, bool OBF16>
__global__ __launch_bounds__(256) void gemm_kernel(
    const ushort_t* __restrict__ A, const ushort_t* __restrict__ W,
    const float* __restrict__ bias, const float* __restrict__ res,
    void* __restrict__ out, int M, int N, int K)
{
    constexpr int WMT = BM / 2, WNT = BN / 2;
    constexpr int FM = WMT / 16, FN = WNT / 16;
    constexpr int ISSA = BM / 64, ISSB = BN / 64;
    __shared__ ushort_t As[BM * 32];
    __shared__ ushort_t Bs[BN * 32];

    const int t = threadIdx.x;
    const int w = t >> 6, lane = t & 63;
    const int wr = w >> 1, wc = w & 1;
    const int col0 = blockIdx.x * BN;
    const int row0 = blockIdx.y * BM;
    const int lrow = lane & 15, kg = lane >> 4;
    const int srow = t >> 2;          // 0..63
    const int skc  = (t & 3) * 8;

    f32x4 acc[FM][FN];
#pragma unroll
    for (int m = 0; m < FM; ++m)
#pragma unroll
        for (int n = 0; n < FN; ++n) acc[m][n] = (f32x4){0.f, 0.f, 0.f, 0.f};

    for (int k0 = 0; k0 < K; k0 += 32) {
#pragma unroll
        for (int i = 0; i < ISSA; ++i)
            gload_lds16(A + (size_t)(row0 + i * 64 + srow) * K + k0 + skc,
                        (char*)As + i * 4096 + t * 16);
#pragma unroll
        for (int i = 0; i < ISSB; ++i)
            gload_lds16(W + (size_t)(col0 + i * 64 + srow) * K + k0 + skc,
                        (char*)Bs + i * 4096 + t * 16);
        __syncthreads();
        short8 af[FM], bfv[FN];
#pragma unroll
        for (int m = 0; m < FM; ++m)
            af[m] = *(const short8*)&As[(wr * WMT + m * 16 + lrow) * 32 + kg * 8];
#pragma unroll
        for (int n = 0; n < FN; ++n)
            bfv[n] = *(const short8*)&Bs[(wc * WNT + n * 16 + lrow) * 32 + kg * 8];
#pragma unroll
        for (int m = 0; m < FM; ++m)
#pragma unroll
            for (int n = 0; n < FN; ++n)
                acc[m][n] = __builtin_amdgcn_mfma_f32_16x16x32_bf16(
                    af[m], bfv[n], acc[m][n], 0, 0, 0);
        __syncthreads();
    }

    const int lrow4 = (lane >> 4) * 4;
    const int lcol  = lane & 15;
#pragma unroll
    for (int m = 0; m < FM; ++m)
#pragma unroll
        for (int n = 0; n < FN; ++n) {
            const int col = col0 + wc * WNT + n * 16 + lcol;
            const float bv = bias ? bias[col] : 0.f;
#pragma unroll
            for (int j = 0; j < 4; ++j) {
                const int row = row0 + wr * WMT + m * 16 + lrow4 + j;
                float v = acc[m][n][j] + bv;
                if (RES)  v += res[(size_t)row * N + col];
                if (RELU) v = fmaxf(v, 0.f);
                if (OBF16) ((ushort_t*)out)[(size_t)row * N + col] = f2bf(v);
                else       ((float*)out)[(size_t)row * N + col] = v;
            }
        }
}

// ---------------------------------------------------------------- attention
// Block: one (b,h), 64-query tile. 4 waves x 16 queries. lane=key for scores,
// lane=d for PV. Q pre-scaled by 1/8. qkv bf16 [4096][1536] (Q|K|V).
__global__ __launch_bounds__(256) void attn_kernel(
    const ushort_t* __restrict__ qkv, const int* __restrict__ am, ushort_t* __restrict__ o)
{
    __shared__ float Qs[64][64];     // stride 64: broadcast reads 16B-aligned
    __shared__ float Ks[64][65];     // stride 65: per-lane scalar reads conflict-free
    __shared__ float Vs[64][65];
    __shared__ float Ps[4][16][64];

    const int t = threadIdx.x, w = t >> 6, lane = t & 63;
    const int bid = blockIdx.x;
    const int qt = 15 - (bid & 15);          // heavy tiles first
    const int bh = bid >> 4, b = bh >> 3, h = bh & 7;
    const int q0 = qt * 64;
    const int w16 = w * 16;

    {   // stage Q (wave-local rows)
        const int r = t >> 2, c0 = (t & 3) * 16;
        const ushort_t* src = qkv + (size_t)(b * SS + q0 + r) * 1536 + h * 64 + c0;
        short8 v0 = *(const short8*)(src);
        short8 v1 = *(const short8*)(src + 8);
#pragma unroll
        for (int j = 0; j < 8; ++j) {
            Qs[r][c0 + j]     = bf2f((ushort_t)v0[j]) * 0.125f;
            Qs[r][c0 + 8 + j] = bf2f((ushort_t)v1[j]) * 0.125f;
        }
    }

    float m_run[16], l_run[16], acc[16];
#pragma unroll
    for (int qq = 0; qq < 16; ++qq) { m_run[qq] = -1e30f; l_run[qq] = 0.f; acc[qq] = 0.f; }

    for (int kt = 0; kt <= qt; ++kt) {
        __syncthreads();
        {   // stage K,V tile (bf16 -> f32)
            const int r = t >> 2, c0 = (t & 3) * 16;
            const ushort_t* ks = qkv + (size_t)(b * SS + kt * 64 + r) * 1536 + 512 + h * 64 + c0;
            short8 k0v = *(const short8*)(ks);
            short8 k1v = *(const short8*)(ks + 8);
            short8 v0v = *(const short8*)(ks + 512);
            short8 v1v = *(const short8*)(ks + 520);
#pragma unroll
            for (int j = 0; j < 8; ++j) {
                Ks[r][c0 + j]     = bf2f((ushort_t)k0v[j]);
                Ks[r][c0 + 8 + j] = bf2f((ushort_t)k1v[j]);
                Vs[r][c0 + j]     = bf2f((ushort_t)v0v[j]);
                Vs[r][c0 + 8 + j] = bf2f((ushort_t)v1v[j]);
            }
        }
        __syncthreads();

        const int kk = kt * 64 + lane;
        const int amv = am[b * SS + kk];
        const bool diag = (kt == qt);

        float s[16];
#pragma unroll
        for (int qq = 0; qq < 16; ++qq) s[qq] = 0.f;
        for (int d0 = 0; d0 < 64; d0 += 4) {
            float kd0 = Ks[lane][d0 + 0], kd1 = Ks[lane][d0 + 1];
            float kd2 = Ks[lane][d0 + 2], kd3 = Ks[lane][d0 + 3];
#pragma unroll
            for (int qq = 0; qq < 16; ++qq) {
                f32x4 qv = *(const f32x4*)&Qs[w16 + qq][d0];
                s[qq] = fmaf(qv.w, kd3, fmaf(qv.z, kd2, fmaf(qv.y, kd1, fmaf(qv.x, kd0, s[qq]))));
            }
        }

#pragma unroll
        for (int qq = 0; qq < 16; ++qq) {
            const int qi = q0 + w16 + qq;
            float sv = (amv != 0 && (!diag || kk <= qi)) ? s[qq] : -1e9f;
            float tmax = sv;
#pragma unroll
            for (int off = 32; off > 0; off >>= 1) tmax = fmaxf(tmax, __shfl_xor(tmax, off));
            float mnew = fmaxf(m_run[qq], tmax);
            float p = __expf(sv - mnew);
            float tsum = p;
#pragma unroll
            for (int off = 32; off > 0; off >>= 1) tsum += __shfl_xor(tsum, off);
            float sc = __expf(m_run[qq] - mnew);
            l_run[qq] = l_run[qq] * sc + tsum;
            acc[qq] *= sc;
            m_run[qq] = mnew;
            Ps[w][qq][lane] = p;
        }

        for (int j0 = 0; j0 < 64; j0 += 4) {
            float v0 = Vs[j0 + 0][lane], v1 = Vs[j0 + 1][lane];
            float v2 = Vs[j0 + 2][lane], v3 = Vs[j0 + 3][lane];
#pragma unroll
            for (int qq = 0; qq < 16; ++qq) {
                f32x4 pv = *(const f32x4*)&Ps[w][qq][j0];
                acc[qq] = fmaf(pv.w, v3, fmaf(pv.z, v2, fmaf(pv.y, v1, fmaf(pv.x, v0, acc[qq]))));
            }
        }
    }

#pragma unroll
    for (int qq = 0; qq < 16; ++qq) {
        const int qi = q0 + w16 + qq;
        o[(size_t)(b * SS + qi) * 512 + h * 64 + lane] = f2bf(acc[qq] / l_run[qq]);
    }
}

// ---------------------------------------------------------------- launch
extern "C" void kernel_launch(void* const* d_in, const int* in_sizes, int n_in,
                              void* d_out, int out_size, void* d_ws, size_t ws_size,
                              hipStream_t stream)
{
    const int*   ids   = (const int*)d_in[0];
    const int*   am    = (const int*)d_in[1];
    const float* emb   = (const float*)d_in[2];
    const float* wq    = (const float*)d_in[3];
    const float* bq    = (const float*)d_in[4];
    const float* wk    = (const float*)d_in[5];
    const float* bk    = (const float*)d_in[6];
    const float* wv    = (const float*)d_in[7];
    const float* bv    = (const float*)d_in[8];
    const float* wo    = (const float*)d_in[9];
    const float* bo    = (const float*)d_in[10];
    const float* ln1g  = (const float*)d_in[11];
    const float* ln1b  = (const float*)d_in[12];
    const float* w1    = (const float*)d_in[13];
    const float* b1    = (const float*)d_in[14];
    const float* w2    = (const float*)d_in[15];
    const float* b2    = (const float*)d_in[16];
    const float* ln2g  = (const float*)d_in[17];
    const float* ln2b  = (const float*)d_in[18];
    const float* lnfg  = (const float*)d_in[19];
    const float* lnfb  = (const float*)d_in[20];
    const float* lmw   = (const float*)d_in[21];

    // ws layout (bytes):
    char* base = (char*)d_ws;
    float*    h    = (float*)(base);                    //  8,388,608
    float*    h2   = (float*)(base + 8388608);          //  8,388,608
    ushort_t* hb   = (ushort_t*)(base + 16777216);      //  4,194,304
    ushort_t* act  = (ushort_t*)(base + 20971520);      // 16,777,216 shared
    ushort_t* qkvb = act;                               //   12 MB
    ushort_t* ob   = act + 6291456;                     //    4 MB
    ushort_t* fbuf = act;                               //   16 MB (after attn phase)
    ushort_t* wl   = (ushort_t*)(base + 37748736);      //  6,291,456
    float*    bqkv = (float*)(base + 44040192);         //      6,144
    ushort_t* lmwb = (ushort_t*)(base + 44046336);      //    524,288
    // total 44,570,624 B

    cvt_simple<<<256, 256, 0, stream>>>(lmw, lmwb);
    embed_kernel<<<NROWS, 512, 0, stream>>>(ids, emb, h, hb);

    for (int l = 0; l < NLAYER; ++l) {
        const size_t dd = (size_t)l * 262144;
        const size_t fd = (size_t)l * 1048576;
        cvt_layer<<<3072, 256, 0, stream>>>(wq + dd, wk + dd, wv + dd, wo + dd,
                                            w1 + fd, w2 + fd,
                                            bq + l * 512, bk + l * 512, bv + l * 512,
                                            wl, bqkv);
        // QKV fused: [4096,1536] = hb @ wqkv^T
        gemm_kernel<128, 128, false, false, true><<<dim3(12, 32), 256, 0, stream>>>(
            hb, wl, bqkv, nullptr, qkvb, NROWS, 1536, 512);

        attn_kernel<<<512, 256, 0, stream>>>(qkvb, am, ob);

        gemm_kernel<64, 128, false, true, false><<<dim3(4, 64), 256, 0, stream>>>(
            ob, wl + 786432, bo + l * 512, h, h2, NROWS, 512, 512);
        ln_kernel<<<NROWS, 512, 0, stream>>>(h2, ln1g + l * 512, ln1b + l * 512, h, hb);

        gemm_kernel<128, 128, true, false, true><<<dim3(16, 32), 256, 0, stream>>>(
            hb, wl + 1048576, b1 + l * 2048, nullptr, fbuf, NROWS, 2048, 512);
        gemm_kernel<64, 128, false, true, false><<<dim3(4, 64), 256, 0, stream>>>(
            fbuf, wl + 2097152, b2 + l * 512, h, h2, NROWS, 512, 2048);
        ln_kernel<<<NROWS, 512, 0, stream>>>(h2, ln2g + l * 512, ln2b + l * 512, h, hb);
    }

    ln_kernel<<<NROWS, 512, 0, stream>>>(h, lnfg, lnfb, h, hb);
    gemm_kernel<64, 128, false, false, false><<<dim3(4, 64), 256, 0, stream>>>(
        hb, lmwb, nullptr, nullptr, d_out, NROWS, 512, 512);
}

// Round 3
// 1108.098 us; speedup vs baseline: 5.8374x; 3.4662x over previous
//
#include <hip/hip_runtime.h>
#include <math.h>

#define D_MODEL 512
#define NHEAD   8
#define DKH     64
#define NLAYER  6
#define FFDIM   2048
#define VOCAB   512
#define BB      4
#define SS      1024
#define NROWS   4096

typedef unsigned short ushort_t;
typedef short short8 __attribute__((ext_vector_type(8)));
typedef float f32x4  __attribute__((ext_vector_type(4)));

__device__ __forceinline__ float bf2f(ushort_t u) {
    union { float f; unsigned int i; } x; x.i = ((unsigned int)u) << 16; return x.f;
}
__device__ __forceinline__ ushort_t f2bf(float f) {
    union { float f; unsigned int i; } x; x.f = f;
    unsigned int r = x.i + 0x7FFFu + ((x.i >> 16) & 1u);
    return (ushort_t)(r >> 16);
}
__device__ __forceinline__ void gload_lds16(const void* g, void* l) {
    __builtin_amdgcn_global_load_lds(
        (const __attribute__((address_space(1))) void*)g,
        (__attribute__((address_space(3))) void*)l, 16, 0, 0);
}

// ------------------------------------------------------------- weight convert
__global__ __launch_bounds__(256) void cvt_layer(
    const float* __restrict__ wq, const float* __restrict__ wk, const float* __restrict__ wv,
    const float* __restrict__ wo, const float* __restrict__ w1, const float* __restrict__ w2,
    const float* __restrict__ bq, const float* __restrict__ bk, const float* __restrict__ bv,
    ushort_t* __restrict__ wl, float* __restrict__ bqkv)
{
    int idx = blockIdx.x * 256 + threadIdx.x;   // quad id, 786432 total
    int e = idx * 4;
    float4 v;
    if (e < 786432) {
        if (e < 262144)       v = *(const float4*)(wq + e);
        else if (e < 524288)  v = *(const float4*)(wk + (e - 262144));
        else                  v = *(const float4*)(wv + (e - 524288));
    } else if (e < 1048576)   v = *(const float4*)(wo + (e - 786432));
    else if (e < 2097152)     v = *(const float4*)(w1 + (e - 1048576));
    else                      v = *(const float4*)(w2 + (e - 2097152));
    union { ushort_t u[4]; uint2 q; } pk;
    pk.u[0] = f2bf(v.x); pk.u[1] = f2bf(v.y); pk.u[2] = f2bf(v.z); pk.u[3] = f2bf(v.w);
    *(uint2*)(wl + e) = pk.q;
    if (idx < 384) {
        int b4 = idx * 4;
        float4 bv4;
        if (b4 < 512)       bv4 = *(const float4*)(bq + b4);
        else if (b4 < 1024) bv4 = *(const float4*)(bk + (b4 - 512));
        else                bv4 = *(const float4*)(bv + (b4 - 1024));
        *(float4*)(bqkv + b4) = bv4;
    }
}

__global__ __launch_bounds__(256) void cvt_simple(
    const float* __restrict__ src, ushort_t* __restrict__ dst)
{
    int e = (blockIdx.x * 256 + threadIdx.x) * 4;
    float4 v = *(const float4*)(src + e);
    union { ushort_t u[4]; uint2 q; } pk;
    pk.u[0] = f2bf(v.x); pk.u[1] = f2bf(v.y); pk.u[2] = f2bf(v.z); pk.u[3] = f2bf(v.w);
    *(uint2*)(dst + e) = pk.q;
}

// ---------------------------------------------------------------- embedding
__global__ __launch_bounds__(512) void embed_kernel(
    const int* __restrict__ ids, const float* __restrict__ emb,
    float* __restrict__ xf, ushort_t* __restrict__ xb)
{
    int row = blockIdx.x;
    int d   = threadIdx.x;
    int s   = row & (SS - 1);
    int tok = ids[row];
    float div = expf(-(float)(d & ~1) * 0.0179889460390586f);
    float arg = (float)s * div;
    float pe  = (d & 1) ? cosf(arg) : sinf(arg);
    float v = emb[(size_t)tok * D_MODEL + d] * 22.62741699796952f + pe;
    xf[(size_t)row * D_MODEL + d] = v;
    xb[(size_t)row * D_MODEL + d] = f2bf(v);
}

// ---------------------------------------------------------------- layernorm
__global__ __launch_bounds__(512) void ln_kernel(
    const float* __restrict__ x, const float* __restrict__ g,
    const float* __restrict__ b, float* __restrict__ outf, ushort_t* __restrict__ outb)
{
    int row = blockIdx.x;
    int d   = threadIdx.x;
    int wave = d >> 6, lane = d & 63;
    __shared__ float red[8];

    float v = x[(size_t)row * D_MODEL + d];
    float s = v;
#pragma unroll
    for (int o = 32; o > 0; o >>= 1) s += __shfl_xor(s, o);
    if (lane == 0) red[wave] = s;
    __syncthreads();
    float tot = 0.f;
#pragma unroll
    for (int i = 0; i < 8; ++i) tot += red[i];
    float mu = tot * (1.0f / D_MODEL);
    float c  = v - mu;
    __syncthreads();
    float s2 = c * c;
#pragma unroll
    for (int o = 32; o > 0; o >>= 1) s2 += __shfl_xor(s2, o);
    if (lane == 0) red[wave] = s2;
    __syncthreads();
    float tot2 = 0.f;
#pragma unroll
    for (int i = 0; i < 8; ++i) tot2 += red[i];
    float var = tot2 * (1.0f / D_MODEL);
    float y = c * (1.0f / sqrtf(var + 1e-5f)) * g[d] + b[d];
    outf[(size_t)row * D_MODEL + d] = y;
    outb[(size_t)row * D_MODEL + d] = f2bf(y);
}

// ---------------------------------------------------------------- MFMA GEMM
template<int BM, int BN, bool RELU, bool RES, bool OBF16>
__global__ __launch_bounds__(256) void gemm_kernel(
    const ushort_t* __restrict__ A, const ushort_t* __restrict__ W,
    const float* __restrict__ bias, const float* __restrict__ res,
    void* __restrict__ out, int M, int N, int K)
{
    constexpr int WMT = BM / 2, WNT = BN / 2;
    constexpr int FM = WMT / 16, FN = WNT / 16;
    constexpr int ISSA = BM / 64, ISSB = BN / 64;
    __shared__ ushort_t As[BM * 32];
    __shared__ ushort_t Bs[BN * 32];

    const int t = threadIdx.x;
    const int w = t >> 6, lane = t & 63;
    const int wr = w >> 1, wc = w & 1;
    const int col0 = blockIdx.x * BN;
    const int row0 = blockIdx.y * BM;
    const int lrow = lane & 15, kg = lane >> 4;
    const int srow = t >> 2;
    const int skc  = (t & 3) * 8;

    f32x4 acc[FM][FN];
#pragma unroll
    for (int m = 0; m < FM; ++m)
#pragma unroll
        for (int n = 0; n < FN; ++n) acc[m][n] = (f32x4){0.f, 0.f, 0.f, 0.f};

    for (int k0 = 0; k0 < K; k0 += 32) {
#pragma unroll
        for (int i = 0; i < ISSA; ++i)
            gload_lds16(A + (size_t)(row0 + i * 64 + srow) * K + k0 + skc,
                        (char*)As + i * 4096 + t * 16);
#pragma unroll
        for (int i = 0; i < ISSB; ++i)
            gload_lds16(W + (size_t)(col0 + i * 64 + srow) * K + k0 + skc,
                        (char*)Bs + i * 4096 + t * 16);
        __syncthreads();
        short8 af[FM], bfv[FN];
#pragma unroll
        for (int m = 0; m < FM; ++m)
            af[m] = *(const short8*)&As[(wr * WMT + m * 16 + lrow) * 32 + kg * 8];
#pragma unroll
        for (int n = 0; n < FN; ++n)
            bfv[n] = *(const short8*)&Bs[(wc * WNT + n * 16 + lrow) * 32 + kg * 8];
#pragma unroll
        for (int m = 0; m < FM; ++m)
#pragma unroll
            for (int n = 0; n < FN; ++n)
                acc[m][n] = __builtin_amdgcn_mfma_f32_16x16x32_bf16(
                    af[m], bfv[n], acc[m][n], 0, 0, 0);
        __syncthreads();
    }

    const int lrow4 = (lane >> 4) * 4;
    const int lcol  = lane & 15;
#pragma unroll
    for (int m = 0; m < FM; ++m)
#pragma unroll
        for (int n = 0; n < FN; ++n) {
            const int col = col0 + wc * WNT + n * 16 + lcol;
            const float bv = bias ? bias[col] : 0.f;
#pragma unroll
            for (int j = 0; j < 4; ++j) {
                const int row = row0 + wr * WMT + m * 16 + lrow4 + j;
                float v = acc[m][n][j] + bv;
                if (RES)  v += res[(size_t)row * N + col];
                if (RELU) v = fmaxf(v, 0.f);
                if (OBF16) ((ushort_t*)out)[(size_t)row * N + col] = f2bf(v);
                else       ((float*)out)[(size_t)row * N + col] = v;
            }
        }
}

// ---------------------------------------------------------------- V transpose
// V (cols 1024..1535 of qkv, per (b,h) [1024 keys][64 d]) -> vtg[bh][64 d][1024 keys]
__global__ __launch_bounds__(256) void vtrans_kernel(
    const ushort_t* __restrict__ qkv, ushort_t* __restrict__ vtg)
{
    __shared__ ushort_t T[64][66];   // 66 ushorts = 33 words: odd stride
    const int t = threadIdx.x;
    const int bid = blockIdx.x;          // 32 bh * 16 kt
    const int kt = bid & 15, bh = bid >> 4, b = bh >> 3, h = bh & 7;
#pragma unroll
    for (int rr = 0; rr < 2; ++rr) {
        int r = (t >> 3) + rr * 32;
        int c = t & 7;
        short8 v = *(const short8*)(qkv + (size_t)(b * SS + kt * 64 + r) * 1536 + 1024 + h * 64 + c * 8);
        *(short8*)&T[r][c * 8] = v;
    }
    __syncthreads();
#pragma unroll
    for (int rr = 0; rr < 2; ++rr) {
        int d  = (t >> 3) + rr * 32;
        int kc = t & 7;
        short8 v;
#pragma unroll
        for (int j = 0; j < 8; ++j) v[j] = (short)T[kc * 8 + j][d];
        *(short8*)(vtg + ((size_t)bh * 64 + d) * 1024 + kt * 64 + kc * 8) = v;
    }
}

// ---------------------------------------------------------------- attention
// MFMA flash attention. Block = (b,h) x 64-query tile; 4 independent waves x 16 q.
// K,V fragments gathered directly from global (L2/L3); only LDS = wave-private P.
__global__ __launch_bounds__(256) void attn_kernel(
    const ushort_t* __restrict__ qkv, const ushort_t* __restrict__ vtg,
    const int* __restrict__ am, ushort_t* __restrict__ o)
{
    __shared__ ushort_t Ps[4][16 * 64];

    const int t = threadIdx.x, w = t >> 6, l = t & 63;
    const int bid = blockIdx.x;
    const int qt = (bid < 256) ? (15 - (bid >> 5)) : ((bid - 256) >> 5);  // balance pairs
    const int bh = bid & 31, b = bh >> 3, h = bh & 7;
    const int q0 = qt * 64;
    const int lg = l >> 4, lr = l & 15;

    // Q A-fragments: rows q0 + w*16 + lr, k-slices lg*8 and 32+lg*8
    const ushort_t* qrow = qkv + (size_t)(b * SS + q0 + w * 16 + lr) * 1536 + h * 64;
    const short8 qa0 = *(const short8*)(qrow + lg * 8);
    const short8 qa1 = *(const short8*)(qrow + 32 + lg * 8);

    float m_run[4], l_run[4];
    f32x4 oacc[4];
#pragma unroll
    for (int j = 0; j < 4; ++j) { m_run[j] = -1e30f; l_run[j] = 0.f; }
#pragma unroll
    for (int nf = 0; nf < 4; ++nf) oacc[nf] = (f32x4){0.f, 0.f, 0.f, 0.f};

    ushort_t* myP = &Ps[w][0];
    const ushort_t* kbase0 = qkv + (size_t)(b * SS) * 1536 + 512 + h * 64;
    const ushort_t* vbase0 = vtg + (size_t)bh * 64 * 1024;
    const int* amrow = am + b * SS;

    for (int kt = 0; kt <= qt; ++kt) {
        // ---- QK^T
        f32x4 s[4];
        const ushort_t* kb = kbase0 + (size_t)(kt * 64 + lr) * 1536;
#pragma unroll
        for (int nf = 0; nf < 4; ++nf) {
            const ushort_t* krow = kb + (size_t)(16 * nf) * 1536;
            short8 kb0 = *(const short8*)(krow + lg * 8);
            short8 kb1 = *(const short8*)(krow + 32 + lg * 8);
            f32x4 a = (f32x4){0.f, 0.f, 0.f, 0.f};
            a = __builtin_amdgcn_mfma_f32_16x16x32_bf16(qa0, kb0, a, 0, 0, 0);
            a = __builtin_amdgcn_mfma_f32_16x16x32_bf16(qa1, kb1, a, 0, 0, 0);
            s[nf] = a;
        }
        // ---- mask + online softmax (per query row j)
        const int kk0 = kt * 64 + lr;
        int amv[4];
#pragma unroll
        for (int nf = 0; nf < 4; ++nf) amv[nf] = amrow[kk0 + 16 * nf];
        const bool diag = (kt == qt);
        float p[4][4];
#pragma unroll
        for (int j = 0; j < 4; ++j) {
            const int qi = q0 + w * 16 + lg * 4 + j;
            float mx = -1e30f;
#pragma unroll
            for (int nf = 0; nf < 4; ++nf) {
                float sv = s[nf][j] * 0.125f;
                bool valid = (amv[nf] != 0) && (!diag || (kk0 + 16 * nf) <= qi);
                sv = valid ? sv : -1e9f;
                s[nf][j] = sv;
                mx = fmaxf(mx, sv);
            }
#pragma unroll
            for (int off = 1; off < 16; off <<= 1) mx = fmaxf(mx, __shfl_xor(mx, off));
            const float mnew = fmaxf(m_run[j], mx);
            float sum = 0.f;
#pragma unroll
            for (int nf = 0; nf < 4; ++nf) {
                float pv = __expf(s[nf][j] - mnew);
                p[nf][j] = pv;
                sum += pv;
            }
#pragma unroll
            for (int off = 1; off < 16; off <<= 1) sum += __shfl_xor(sum, off);
            const float rs = __expf(m_run[j] - mnew);
            l_run[j] = l_run[j] * rs + sum;
            m_run[j] = mnew;
#pragma unroll
            for (int nf = 0; nf < 4; ++nf) oacc[nf][j] *= rs;
        }
        // ---- write P (bf16, chunk-XOR swizzle), wave-private: no barrier
#pragma unroll
        for (int nf = 0; nf < 4; ++nf)
#pragma unroll
            for (int j = 0; j < 4; ++j) {
                const int q = lg * 4 + j;
                const int col = nf * 16 + lr;
                myP[q * 64 + (((col >> 3) ^ (q & 7)) << 3) + (col & 7)] = f2bf(p[nf][j]);
            }
        asm volatile("s_waitcnt lgkmcnt(0)" ::: "memory");
        __builtin_amdgcn_sched_barrier(0);
        // ---- read P A-fragments
        const short8 pa0 = *(const short8*)&myP[lr * 64 + ((lg ^ (lr & 7)) << 3)];
        const short8 pa1 = *(const short8*)&myP[lr * 64 + (((4 + lg) ^ (lr & 7)) << 3)];
        // ---- PV with transposed V fragments
        const ushort_t* vb = vbase0 + (size_t)lr * 1024 + kt * 64 + lg * 8;
#pragma unroll
        for (int nf = 0; nf < 4; ++nf) {
            const ushort_t* vrow = vb + (size_t)(16 * nf) * 1024;
            short8 vb0 = *(const short8*)(vrow);
            short8 vb1 = *(const short8*)(vrow + 32);
            oacc[nf] = __builtin_amdgcn_mfma_f32_16x16x32_bf16(pa0, vb0, oacc[nf], 0, 0, 0);
            oacc[nf] = __builtin_amdgcn_mfma_f32_16x16x32_bf16(pa1, vb1, oacc[nf], 0, 0, 0);
        }
    }

#pragma unroll
    for (int nf = 0; nf < 4; ++nf)
#pragma unroll
        for (int j = 0; j < 4; ++j) {
            const int qi = q0 + w * 16 + lg * 4 + j;
            const int d  = nf * 16 + lr;
            o[(size_t)(b * SS + qi) * 512 + h * 64 + d] = f2bf(oacc[nf][j] / l_run[j]);
        }
}

// ---------------------------------------------------------------- launch
extern "C" void kernel_launch(void* const* d_in, const int* in_sizes, int n_in,
                              void* d_out, int out_size, void* d_ws, size_t ws_size,
                              hipStream_t stream)
{
    const int*   ids   = (const int*)d_in[0];
    const int*   am    = (const int*)d_in[1];
    const float* emb   = (const float*)d_in[2];
    const float* wq    = (const float*)d_in[3];
    const float* bq    = (const float*)d_in[4];
    const float* wk    = (const float*)d_in[5];
    const float* bk    = (const float*)d_in[6];
    const float* wv    = (const float*)d_in[7];
    const float* bv    = (const float*)d_in[8];
    const float* wo    = (const float*)d_in[9];
    const float* bo    = (const float*)d_in[10];
    const float* ln1g  = (const float*)d_in[11];
    const float* ln1b  = (const float*)d_in[12];
    const float* w1    = (const float*)d_in[13];
    const float* b1    = (const float*)d_in[14];
    const float* w2    = (const float*)d_in[15];
    const float* b2    = (const float*)d_in[16];
    const float* ln2g  = (const float*)d_in[17];
    const float* ln2b  = (const float*)d_in[18];
    const float* lnfg  = (const float*)d_in[19];
    const float* lnfb  = (const float*)d_in[20];
    const float* lmw   = (const float*)d_in[21];

    char* base = (char*)d_ws;
    float*    h    = (float*)(base);                    //  8,388,608
    float*    h2   = (float*)(base + 8388608);          //  8,388,608 (aliased by vtg during attn)
    ushort_t* hb   = (ushort_t*)(base + 16777216);      //  4,194,304
    ushort_t* act  = (ushort_t*)(base + 20971520);      // 16,777,216 shared
    ushort_t* qkvb = act;                               //   12 MB
    ushort_t* ob   = act + 6291456;                     //    4 MB
    ushort_t* fbuf = act;                               //   16 MB (after attn phase)
    ushort_t* wl   = (ushort_t*)(base + 37748736);      //  6,291,456
    float*    bqkv = (float*)(base + 44040192);         //      6,144
    ushort_t* lmwb = (ushort_t*)(base + 44046336);      //    524,288
    ushort_t* vtg  = (ushort_t*)h2;                     //    4 MB, live only during attn

    cvt_simple<<<256, 256, 0, stream>>>(lmw, lmwb);
    embed_kernel<<<NROWS, 512, 0, stream>>>(ids, emb, h, hb);

    for (int l = 0; l < NLAYER; ++l) {
        const size_t dd = (size_t)l * 262144;
        const size_t fd = (size_t)l * 1048576;
        cvt_layer<<<3072, 256, 0, stream>>>(wq + dd, wk + dd, wv + dd, wo + dd,
                                            w1 + fd, w2 + fd,
                                            bq + l * 512, bk + l * 512, bv + l * 512,
                                            wl, bqkv);
        gemm_kernel<128, 128, false, false, true><<<dim3(12, 32), 256, 0, stream>>>(
            hb, wl, bqkv, nullptr, qkvb, NROWS, 1536, 512);

        vtrans_kernel<<<512, 256, 0, stream>>>(qkvb, vtg);
        attn_kernel<<<512, 256, 0, stream>>>(qkvb, vtg, am, ob);

        gemm_kernel<64, 128, false, true, false><<<dim3(4, 64), 256, 0, stream>>>(
            ob, wl + 786432, bo + l * 512, h, h2, NROWS, 512, 512);
        ln_kernel<<<NROWS, 512, 0, stream>>>(h2, ln1g + l * 512, ln1b + l * 512, h, hb);

        gemm_kernel<128, 128, true, false, true><<<dim3(16, 32), 256, 0, stream>>>(
            hb, wl + 1048576, b1 + l * 2048, nullptr, fbuf, NROWS, 2048, 512);
        gemm_kernel<64, 128, false, true, false><<<dim3(4, 64), 256, 0, stream>>>(
            fbuf, wl + 2097152, b2 + l * 512, h, h2, NROWS, 512, 2048);
        ln_kernel<<<NROWS, 512, 0, stream>>>(h2, ln2g + l * 512, ln2b + l * 512, h, hb);
    }

    ln_kernel<<<NROWS, 512, 0, stream>>>(h, lnfg, lnfb, h, hb);
    gemm_kernel<64, 128, false, false, false><<<dim3(4, 64), 256, 0, stream>>>(
        hb, lmwb, nullptr, nullptr, d_out, NROWS, 512, 512);
}

// Round 4
// 982.155 us; speedup vs baseline: 6.5859x; 1.1282x over previous
//
#include <hip/hip_runtime.h>
#include <math.h>

#define D_MODEL 512
#define NHEAD   8
#define DKH     64
#define NLAYER  6
#define FFDIM   2048
#define VOCAB   512
#define BB      4
#define SS      1024
#define NROWS   4096

typedef unsigned short ushort_t;
typedef short short8 __attribute__((ext_vector_type(8)));
typedef float f32x4  __attribute__((ext_vector_type(4)));

__device__ __forceinline__ float bf2f(ushort_t u) {
    union { float f; unsigned int i; } x; x.i = ((unsigned int)u) << 16; return x.f;
}
__device__ __forceinline__ ushort_t f2bf(float f) {
    union { float f; unsigned int i; } x; x.f = f;
    unsigned int r = x.i + 0x7FFFu + ((x.i >> 16) & 1u);
    return (ushort_t)(r >> 16);
}
__device__ __forceinline__ void gload_lds16(const void* g, void* l) {
    __builtin_amdgcn_global_load_lds(
        (const __attribute__((address_space(1))) void*)g,
        (__attribute__((address_space(3))) void*)l, 16, 0, 0);
}

// ------------------------------------------------------------- weight convert
__global__ __launch_bounds__(256) void cvt_layer(
    const float* __restrict__ wq, const float* __restrict__ wk, const float* __restrict__ wv,
    const float* __restrict__ wo, const float* __restrict__ w1, const float* __restrict__ w2,
    const float* __restrict__ bq, const float* __restrict__ bk, const float* __restrict__ bv,
    ushort_t* __restrict__ wl, float* __restrict__ bqkv)
{
    int idx = blockIdx.x * 256 + threadIdx.x;   // quad id, 786432 total
    int e = idx * 4;
    float4 v;
    if (e < 786432) {
        if (e < 262144)       v = *(const float4*)(wq + e);
        else if (e < 524288)  v = *(const float4*)(wk + (e - 262144));
        else                  v = *(const float4*)(wv + (e - 524288));
    } else if (e < 1048576)   v = *(const float4*)(wo + (e - 786432));
    else if (e < 2097152)     v = *(const float4*)(w1 + (e - 1048576));
    else                      v = *(const float4*)(w2 + (e - 2097152));
    union { ushort_t u[4]; uint2 q; } pk;
    pk.u[0] = f2bf(v.x); pk.u[1] = f2bf(v.y); pk.u[2] = f2bf(v.z); pk.u[3] = f2bf(v.w);
    *(uint2*)(wl + e) = pk.q;
    if (idx < 384) {
        int b4 = idx * 4;
        float4 bv4;
        if (b4 < 512)       bv4 = *(const float4*)(bq + b4);
        else if (b4 < 1024) bv4 = *(const float4*)(bk + (b4 - 512));
        else                bv4 = *(const float4*)(bv + (b4 - 1024));
        *(float4*)(bqkv + b4) = bv4;
    }
}

__global__ __launch_bounds__(256) void cvt_simple(
    const float* __restrict__ src, ushort_t* __restrict__ dst)
{
    int e = (blockIdx.x * 256 + threadIdx.x) * 4;
    float4 v = *(const float4*)(src + e);
    union { ushort_t u[4]; uint2 q; } pk;
    pk.u[0] = f2bf(v.x); pk.u[1] = f2bf(v.y); pk.u[2] = f2bf(v.z); pk.u[3] = f2bf(v.w);
    *(uint2*)(dst + e) = pk.q;
}

// mask bias: am ? 0 : -1e9  (tiny, L1-resident during attention)
__global__ __launch_bounds__(256) void maskbias_kernel(
    const int* __restrict__ am, float* __restrict__ mb)
{
    int i = blockIdx.x * 256 + threadIdx.x;
    if (i < NROWS) mb[i] = am[i] ? 0.f : -1e9f;
}

// ---------------------------------------------------------------- embedding
__global__ __launch_bounds__(512) void embed_kernel(
    const int* __restrict__ ids, const float* __restrict__ emb,
    float* __restrict__ xf, ushort_t* __restrict__ xb)
{
    int row = blockIdx.x;
    int d   = threadIdx.x;
    int s   = row & (SS - 1);
    int tok = ids[row];
    float div = expf(-(float)(d & ~1) * 0.0179889460390586f);
    float arg = (float)s * div;
    float pe  = (d & 1) ? cosf(arg) : sinf(arg);
    float v = emb[(size_t)tok * D_MODEL + d] * 22.62741699796952f + pe;
    xf[(size_t)row * D_MODEL + d] = v;
    xb[(size_t)row * D_MODEL + d] = f2bf(v);
}

// ---------------------------------------------------------------- layernorm
__global__ __launch_bounds__(512) void ln_kernel(
    const float* __restrict__ x, const float* __restrict__ g,
    const float* __restrict__ b, float* __restrict__ outf, ushort_t* __restrict__ outb)
{
    int row = blockIdx.x;
    int d   = threadIdx.x;
    int wave = d >> 6, lane = d & 63;
    __shared__ float red[8];

    float v = x[(size_t)row * D_MODEL + d];
    float s = v;
#pragma unroll
    for (int o = 32; o > 0; o >>= 1) s += __shfl_xor(s, o);
    if (lane == 0) red[wave] = s;
    __syncthreads();
    float tot = 0.f;
#pragma unroll
    for (int i = 0; i < 8; ++i) tot += red[i];
    float mu = tot * (1.0f / D_MODEL);
    float c  = v - mu;
    __syncthreads();
    float s2 = c * c;
#pragma unroll
    for (int o = 32; o > 0; o >>= 1) s2 += __shfl_xor(s2, o);
    if (lane == 0) red[wave] = s2;
    __syncthreads();
    float tot2 = 0.f;
#pragma unroll
    for (int i = 0; i < 8; ++i) tot2 += red[i];
    float var = tot2 * (1.0f / D_MODEL);
    float y = c * (1.0f / sqrtf(var + 1e-5f)) * g[d] + b[d];
    outf[(size_t)row * D_MODEL + d] = y;
    outb[(size_t)row * D_MODEL + d] = f2bf(y);
}

// ---------------------------------------------------------------- MFMA GEMM
template<int BM, int BN, bool RELU, bool RES, bool OBF16>
__global__ __launch_bounds__(256) void gemm_kernel(
    const ushort_t* __restrict__ A, const ushort_t* __restrict__ W,
    const float* __restrict__ bias, const float* __restrict__ res,
    void* __restrict__ out, int M, int N, int K)
{
    constexpr int WMT = BM / 2, WNT = BN / 2;
    constexpr int FM = WMT / 16, FN = WNT / 16;
    constexpr int ISSA = BM / 64, ISSB = BN / 64;
    __shared__ ushort_t As[BM * 32];
    __shared__ ushort_t Bs[BN * 32];

    const int t = threadIdx.x;
    const int w = t >> 6, lane = t & 63;
    const int wr = w >> 1, wc = w & 1;
    const int col0 = blockIdx.x * BN;
    const int row0 = blockIdx.y * BM;
    const int lrow = lane & 15, kg = lane >> 4;
    const int srow = t >> 2;
    const int skc  = (t & 3) * 8;

    f32x4 acc[FM][FN];
#pragma unroll
    for (int m = 0; m < FM; ++m)
#pragma unroll
        for (int n = 0; n < FN; ++n) acc[m][n] = (f32x4){0.f, 0.f, 0.f, 0.f};

    for (int k0 = 0; k0 < K; k0 += 32) {
#pragma unroll
        for (int i = 0; i < ISSA; ++i)
            gload_lds16(A + (size_t)(row0 + i * 64 + srow) * K + k0 + skc,
                        (char*)As + i * 4096 + t * 16);
#pragma unroll
        for (int i = 0; i < ISSB; ++i)
            gload_lds16(W + (size_t)(col0 + i * 64 + srow) * K + k0 + skc,
                        (char*)Bs + i * 4096 + t * 16);
        __syncthreads();
        short8 af[FM], bfv[FN];
#pragma unroll
        for (int m = 0; m < FM; ++m)
            af[m] = *(const short8*)&As[(wr * WMT + m * 16 + lrow) * 32 + kg * 8];
#pragma unroll
        for (int n = 0; n < FN; ++n)
            bfv[n] = *(const short8*)&Bs[(wc * WNT + n * 16 + lrow) * 32 + kg * 8];
#pragma unroll
        for (int m = 0; m < FM; ++m)
#pragma unroll
            for (int n = 0; n < FN; ++n)
                acc[m][n] = __builtin_amdgcn_mfma_f32_16x16x32_bf16(
                    af[m], bfv[n], acc[m][n], 0, 0, 0);
        __syncthreads();
    }

    const int lrow4 = (lane >> 4) * 4;
    const int lcol  = lane & 15;
#pragma unroll
    for (int m = 0; m < FM; ++m)
#pragma unroll
        for (int n = 0; n < FN; ++n) {
            const int col = col0 + wc * WNT + n * 16 + lcol;
            const float bv = bias ? bias[col] : 0.f;
#pragma unroll
            for (int j = 0; j < 4; ++j) {
                const int row = row0 + wr * WMT + m * 16 + lrow4 + j;
                float v = acc[m][n][j] + bv;
                if (RES)  v += res[(size_t)row * N + col];
                if (RELU) v = fmaxf(v, 0.f);
                if (OBF16) ((ushort_t*)out)[(size_t)row * N + col] = f2bf(v);
                else       ((float*)out)[(size_t)row * N + col] = v;
            }
        }
}

// ---------------------------------------------------------------- V transpose
__global__ __launch_bounds__(256) void vtrans_kernel(
    const ushort_t* __restrict__ qkv, ushort_t* __restrict__ vtg)
{
    __shared__ ushort_t T[64][66];
    const int t = threadIdx.x;
    const int bid = blockIdx.x;          // 32 bh * 16 kt
    const int kt = bid & 15, bh = bid >> 4, b = bh >> 3, h = bh & 7;
#pragma unroll
    for (int rr = 0; rr < 2; ++rr) {
        int r = (t >> 3) + rr * 32;
        int c = t & 7;
        short8 v = *(const short8*)(qkv + (size_t)(b * SS + kt * 64 + r) * 1536 + 1024 + h * 64 + c * 8);
        *(short8*)&T[r][c * 8] = v;
    }
    __syncthreads();
#pragma unroll
    for (int rr = 0; rr < 2; ++rr) {
        int d  = (t >> 3) + rr * 32;
        int kc = t & 7;
        short8 v;
#pragma unroll
        for (int j = 0; j < 8; ++j) v[j] = (short)T[kc * 8 + j][d];
        *(short8*)(vtg + ((size_t)bh * 64 + d) * 1024 + kt * 64 + kc * 8) = v;
    }
}

// ---------------------------------------------------------------- attention
// MFMA flash attention. Block = (b,h) x 64-query tile; 4 independent waves x 16 q.
// K register-double-buffered (prefetch kt+1 one full iter ahead); V loaded
// just-in-time at iteration top (consumed ~600cy later, after softmax+P);
// mask as prefetched f32 bias (L1). Only LDS = wave-private swizzled P.
__global__ __launch_bounds__(256) void attn_kernel(
    const ushort_t* __restrict__ qkv, const ushort_t* __restrict__ vtg,
    const float* __restrict__ mbias, ushort_t* __restrict__ o)
{
    __shared__ ushort_t Ps[4][16 * 64];

    const int t = threadIdx.x, w = t >> 6, l = t & 63;
    const int bid = blockIdx.x;
    const int qt = (bid < 256) ? (15 - (bid >> 5)) : ((bid - 256) >> 5);  // balance
    const int bh = bid & 31, b = bh >> 3, h = bh & 7;
    const int q0 = qt * 64;
    const int lg = l >> 4, lr = l & 15;

    const ushort_t* qrow = qkv + (size_t)(b * SS + q0 + w * 16 + lr) * 1536 + h * 64;
    const short8 qa0 = *(const short8*)(qrow + lg * 8);
    const short8 qa1 = *(const short8*)(qrow + 32 + lg * 8);

    float m_run[4], l_run[4];
    f32x4 oacc[4];
#pragma unroll
    for (int j = 0; j < 4; ++j) { m_run[j] = -1e30f; l_run[j] = 0.f; }
#pragma unroll
    for (int nf = 0; nf < 4; ++nf) oacc[nf] = (f32x4){0.f, 0.f, 0.f, 0.f};

    ushort_t* myP = &Ps[w][0];
    // per-lane bases
    const ushort_t* kb0 = qkv + (size_t)(b * SS) * 1536 + 512 + h * 64 + (size_t)lr * 1536 + lg * 8;
    const ushort_t* vb0 = vtg + ((size_t)bh * 64 + lr) * 1024 + lg * 8;
    const float*    mb0 = mbias + b * SS + lr;

    short8 kA[8], kB[8];
    float  mbA[4], mbB[4];

    auto PREFK = [&](short8* kf, float* mbf, int kt) {
#pragma unroll
        for (int nf = 0; nf < 4; ++nf) {
            const ushort_t* kr = kb0 + (size_t)(kt * 64 + 16 * nf) * 1536;
            kf[2 * nf]     = *(const short8*)(kr);
            kf[2 * nf + 1] = *(const short8*)(kr + 32);
            mbf[nf] = mb0[kt * 64 + 16 * nf];
        }
    };

    auto COMPUTE = [&](const short8* kf, const float* mbf, int kt) {
        // V just-in-time: consumed after softmax + P round-trip
        short8 vf[8];
#pragma unroll
        for (int nf = 0; nf < 4; ++nf) {
            const ushort_t* vr = vb0 + (size_t)(16 * nf) * 1024 + kt * 64;
            vf[2 * nf]     = *(const short8*)(vr);
            vf[2 * nf + 1] = *(const short8*)(vr + 32);
        }
        // QK^T (K fragments already resident)
        f32x4 s[4];
#pragma unroll
        for (int nf = 0; nf < 4; ++nf) {
            f32x4 a = (f32x4){0.f, 0.f, 0.f, 0.f};
            a = __builtin_amdgcn_mfma_f32_16x16x32_bf16(qa0, kf[2 * nf],     a, 0, 0, 0);
            a = __builtin_amdgcn_mfma_f32_16x16x32_bf16(qa1, kf[2 * nf + 1], a, 0, 0, 0);
            s[nf] = a;
        }
        // mask + online softmax
        const int kk0 = kt * 64 + lr;
        const bool diag = (kt == qt);
        float p[4][4];
#pragma unroll
        for (int j = 0; j < 4; ++j) {
            const int qi = q0 + w * 16 + lg * 4 + j;
            float mx = -1e30f;
#pragma unroll
            for (int nf = 0; nf < 4; ++nf) {
                float sv = s[nf][j] * 0.125f + mbf[nf];
                if (diag && (kk0 + 16 * nf) > qi) sv = -1e9f;
                s[nf][j] = sv;
                mx = fmaxf(mx, sv);
            }
#pragma unroll
            for (int off = 1; off < 16; off <<= 1) mx = fmaxf(mx, __shfl_xor(mx, off));
            const float mnew = fmaxf(m_run[j], mx);
            float sum = 0.f;
#pragma unroll
            for (int nf = 0; nf < 4; ++nf) {
                float pv = __expf(s[nf][j] - mnew);
                p[nf][j] = pv;
                sum += pv;
            }
#pragma unroll
            for (int off = 1; off < 16; off <<= 1) sum += __shfl_xor(sum, off);
            const float rs = __expf(m_run[j] - mnew);
            l_run[j] = l_run[j] * rs + sum;
            m_run[j] = mnew;
#pragma unroll
            for (int nf = 0; nf < 4; ++nf) oacc[nf][j] *= rs;
        }
        // P -> LDS (bf16, chunk-XOR swizzle), wave-private: no barrier
#pragma unroll
        for (int nf = 0; nf < 4; ++nf)
#pragma unroll
            for (int j = 0; j < 4; ++j) {
                const int q = lg * 4 + j;
                const int col = nf * 16 + lr;
                myP[q * 64 + (((col >> 3) ^ (q & 7)) << 3) + (col & 7)] = f2bf(p[nf][j]);
            }
        asm volatile("s_waitcnt lgkmcnt(0)" ::: "memory");
        __builtin_amdgcn_sched_barrier(0);
        const short8 pa0 = *(const short8*)&myP[lr * 64 + ((lg ^ (lr & 7)) << 3)];
        const short8 pa1 = *(const short8*)&myP[lr * 64 + (((4 + lg) ^ (lr & 7)) << 3)];
        // PV (V loads issued ~600cy ago)
#pragma unroll
        for (int nf = 0; nf < 4; ++nf) {
            oacc[nf] = __builtin_amdgcn_mfma_f32_16x16x32_bf16(pa0, vf[2 * nf],     oacc[nf], 0, 0, 0);
            oacc[nf] = __builtin_amdgcn_mfma_f32_16x16x32_bf16(pa1, vf[2 * nf + 1], oacc[nf], 0, 0, 0);
        }
    };

    PREFK(kA, mbA, 0);
    for (int kt = 0; kt <= qt; kt += 2) {
        PREFK(kB, mbB, (kt + 1 <= qt) ? kt + 1 : qt);
        COMPUTE(kA, mbA, kt);
        if (kt + 1 <= qt) {
            PREFK(kA, mbA, (kt + 2 <= qt) ? kt + 2 : qt);
            COMPUTE(kB, mbB, kt + 1);
        }
    }

#pragma unroll
    for (int nf = 0; nf < 4; ++nf)
#pragma unroll
        for (int j = 0; j < 4; ++j) {
            const int qi = q0 + w * 16 + lg * 4 + j;
            const int d  = nf * 16 + lr;
            o[(size_t)(b * SS + qi) * 512 + h * 64 + d] = f2bf(oacc[nf][j] / l_run[j]);
        }
}

// ---------------------------------------------------------------- launch
extern "C" void kernel_launch(void* const* d_in, const int* in_sizes, int n_in,
                              void* d_out, int out_size, void* d_ws, size_t ws_size,
                              hipStream_t stream)
{
    const int*   ids   = (const int*)d_in[0];
    const int*   am    = (const int*)d_in[1];
    const float* emb   = (const float*)d_in[2];
    const float* wq    = (const float*)d_in[3];
    const float* bq    = (const float*)d_in[4];
    const float* wk    = (const float*)d_in[5];
    const float* bk    = (const float*)d_in[6];
    const float* wv    = (const float*)d_in[7];
    const float* bv    = (const float*)d_in[8];
    const float* wo    = (const float*)d_in[9];
    const float* bo    = (const float*)d_in[10];
    const float* ln1g  = (const float*)d_in[11];
    const float* ln1b  = (const float*)d_in[12];
    const float* w1    = (const float*)d_in[13];
    const float* b1    = (const float*)d_in[14];
    const float* w2    = (const float*)d_in[15];
    const float* b2    = (const float*)d_in[16];
    const float* ln2g  = (const float*)d_in[17];
    const float* ln2b  = (const float*)d_in[18];
    const float* lnfg  = (const float*)d_in[19];
    const float* lnfb  = (const float*)d_in[20];
    const float* lmw   = (const float*)d_in[21];

    char* base = (char*)d_ws;
    float*    h    = (float*)(base);                    //  8,388,608
    float*    h2   = (float*)(base + 8388608);          //  8,388,608 (aliased by vtg during attn)
    ushort_t* hb   = (ushort_t*)(base + 16777216);      //  4,194,304
    ushort_t* act  = (ushort_t*)(base + 20971520);      // 16,777,216 shared
    ushort_t* qkvb = act;                               //   12 MB
    ushort_t* ob   = act + 6291456;                     //    4 MB
    ushort_t* fbuf = act;                               //   16 MB (after attn phase)
    ushort_t* wl   = (ushort_t*)(base + 37748736);      //  6,291,456
    float*    bqkv = (float*)(base + 44040192);         //      6,144
    ushort_t* lmwb = (ushort_t*)(base + 44046336);      //    524,288
    float*    mbias= (float*)(base + 44570624);         //     16,384
    ushort_t* vtg  = (ushort_t*)h2;                     //    4 MB, live only during attn

    cvt_simple<<<256, 256, 0, stream>>>(lmw, lmwb);
    maskbias_kernel<<<16, 256, 0, stream>>>(am, mbias);
    embed_kernel<<<NROWS, 512, 0, stream>>>(ids, emb, h, hb);

    for (int l = 0; l < NLAYER; ++l) {
        const size_t dd = (size_t)l * 262144;
        const size_t fd = (size_t)l * 1048576;
        cvt_layer<<<3072, 256, 0, stream>>>(wq + dd, wk + dd, wv + dd, wo + dd,
                                            w1 + fd, w2 + fd,
                                            bq + l * 512, bk + l * 512, bv + l * 512,
                                            wl, bqkv);
        gemm_kernel<128, 128, false, false, true><<<dim3(12, 32), 256, 0, stream>>>(
            hb, wl, bqkv, nullptr, qkvb, NROWS, 1536, 512);

        vtrans_kernel<<<512, 256, 0, stream>>>(qkvb, vtg);
        attn_kernel<<<512, 256, 0, stream>>>(qkvb, vtg, mbias, ob);

        gemm_kernel<64, 128, false, true, false><<<dim3(4, 64), 256, 0, stream>>>(
            ob, wl + 786432, bo + l * 512, h, h2, NROWS, 512, 512);
        ln_kernel<<<NROWS, 512, 0, stream>>>(h2, ln1g + l * 512, ln1b + l * 512, h, hb);

        gemm_kernel<128, 128, true, false, true><<<dim3(16, 32), 256, 0, stream>>>(
            hb, wl + 1048576, b1 + l * 2048, nullptr, fbuf, NROWS, 2048, 512);
        gemm_kernel<64, 128, false, true, false><<<dim3(4, 64), 256, 0, stream>>>(
            fbuf, wl + 2097152, b2 + l * 512, h, h2, NROWS, 512, 2048);
        ln_kernel<<<NROWS, 512, 0, stream>>>(h2, ln2g + l * 512, ln2b + l * 512, h, hb);
    }

    ln_kernel<<<NROWS, 512, 0, stream>>>(h, lnfg, lnfb, h, hb);
    gemm_kernel<64, 128, false, false, false><<<dim3(4, 64), 256, 0, stream>>>(
        hb, lmwb, nullptr, nullptr, d_out, NROWS, 512, 512);
}